// Round 3
// baseline (724.441 us; speedup 1.0000x reference)
//
#include <hip/hip_runtime.h>

// LiftSplatShoot voxel pooling, B=1, N=6, D=41, H=64, W=176, C=32, grid 200x200x1.
// nprime = 2,770,944 points. rank = ix*200 + iy (nx2=1, B=1).
// out[c*40000 + ix*200 + iy] = sum over points in voxel (ix,iy) of x[p][c].
//
// R6 (3921->611us): replaced 88.7M contended f32 atomics with linked-list
// build (1 atomicExch per kept point) + per-voxel gather.
// R8: rocprof shows the timed region contains a harness ws-poison fill
// (1.419 GB, ~216us @82% HBM peak) we cannot remove; our build+gather ~380us
// vs ~100us BW floor. Gather's p=next[p] chase is a serially-dependent load
// chain (one ~400-900cy miss per link, ~26 deep, ~2 loads in flight/wave).
// Replace with CSR buckets: atomicAdd slot + bucket[v*256+slot]=p, then a
// gather whose index loads have NO serial dependence -> full MLP, pure BW.

#define NVOX   40000
#define NCH    32
#define MAXPTS 256   // Poisson mean ~52 pts/voxel; 256 is ~28 sigma. Overflow
                     // (never expected) goes through f32 atomics into extra[].

__device__ __forceinline__ void atomic_add_agent(float* p, float v) {
    __hip_atomic_fetch_add(p, v, __ATOMIC_RELAXED, __HIP_MEMORY_SCOPE_AGENT);
}

__device__ __forceinline__ int voxel_of(const float* __restrict__ geom, int p) {
    // Exact reference arithmetic: t = (g - (bx - dx/2)) / dx, trunc toward zero.
    float gx = geom[3 * (size_t)p + 0];
    float gy = geom[3 * (size_t)p + 1];
    float gz = geom[3 * (size_t)p + 2];
    float tx = (gx + 50.0f) / 0.5f;   // lo_x = -50 exact; /0.5 exact
    float ty = (gy + 50.0f) / 0.5f;
    float tz = (gz + 10.0f) / 20.0f;  // correctly-rounded IEEE f32 division
    int ix = (int)tx;  // trunc toward zero == astype(int32); (-1,0) -> 0 kept
    int iy = (int)ty;
    int iz = (int)tz;
    if (!((ix >= 0) && (ix < 200) && (iy >= 0) && (iy < 200) && (iz == 0)))
        return -1;
    return ix * 200 + iy;
}

// ---------------- fast path: CSR bucket build + streaming gather -----------

// cnt:   [NVOX]       per-voxel point count (memset 0 per iter)
// extra: [NVOX*NCH]   f32 overflow accumulator (memset 0 per iter; never hit)
// bucket:[NVOX*MAXPTS] point indices, no init needed
__global__ void __launch_bounds__(256)
lss_count(const float* __restrict__ geom, const float* __restrict__ x,
          int* __restrict__ cnt, float* __restrict__ extra,
          int* __restrict__ bucket, int nprime) {
    int p = blockIdx.x * blockDim.x + threadIdx.x;
    if (p >= nprime) return;
    int v = voxel_of(geom, p);
    if (v < 0) return;
    int slot = __hip_atomic_fetch_add(&cnt[v], 1,
                                      __ATOMIC_RELAXED, __HIP_MEMORY_SCOPE_AGENT);
    if (slot < MAXPTS) {
        bucket[(size_t)v * MAXPTS + slot] = p;
    } else {  // statistically unreachable; correctness insurance
        const float* row = x + (size_t)p * NCH;
        for (int k = 0; k < NCH; ++k)
            atomic_add_agent(&extra[(size_t)v * NCH + k], row[k]);
    }
}

// One wave per voxel. lane = half*32 + c; half-wave h walks slots h, h+2, ...
// Index loads are at known addresses (no chase) -> many x-row loads in flight.
__global__ void __launch_bounds__(256)
lss_gather_csr(const float* __restrict__ x, const int* __restrict__ cnt,
               const float* __restrict__ extra, const int* __restrict__ bucket,
               float* __restrict__ out, int nprime) {
    int wv = blockIdx.x * (blockDim.x >> 6) + (threadIdx.x >> 6);  // voxel
    if (wv >= NVOX) return;
    int lane = threadIdx.x & 63;
    int half = lane >> 5;   // which slot parity this half-wave owns
    int c    = lane & 31;   // channel

    int total = cnt[wv];
    int n = total < MAXPTS ? total : MAXPTS;
    const int* base = bucket + (size_t)wv * MAXPTS;

    float acc = 0.0f;
    #pragma unroll 4
    for (int i = half; i < n; i += 2) {
        int p = base[i];                    // 32 lanes same addr -> broadcast
        if ((unsigned)p < (unsigned)nprime) // insurance vs poisoned ws replay
            acc += x[(size_t)p * NCH + c];  // 128B coalesced row read
    }
    acc += __shfl_xor(acc, 32);             // combine the two halves
    if (lane < 32) {
        float r = acc;
        if (total > MAXPTS) r += extra[(size_t)wv * NCH + c];
        out[(size_t)c * NVOX + wv] = r;     // (C, 200, 200) layout, all written
    }
}

// ---------------- tier 2: linked-list path (proven R7) ---------------------

__global__ void __launch_bounds__(256)
lss_build(const float* __restrict__ geom, int* __restrict__ head2,
          int* __restrict__ next, int nprime) {
    int p = blockIdx.x * blockDim.x + threadIdx.x;
    if (p >= nprime) return;
    int v = voxel_of(geom, p);
    if (v < 0) return;
    int slot = (p & 1) * NVOX + v;
    int old = __hip_atomic_exchange(&head2[slot], p,
                                    __ATOMIC_RELAXED, __HIP_MEMORY_SCOPE_AGENT);
    next[p] = old;   // consumed only by the next kernel launch -> no race
}

__global__ void __launch_bounds__(256)
lss_gather(const float* __restrict__ x, const int* __restrict__ head2,
           const int* __restrict__ next, float* __restrict__ out, int nprime) {
    int wv = blockIdx.x * (blockDim.x >> 6) + (threadIdx.x >> 6);  // voxel
    if (wv >= NVOX) return;
    int lane = threadIdx.x & 63;
    int half = lane >> 5;
    int c    = lane & 31;

    float acc = 0.0f;
    int p = head2[half * NVOX + wv];
    int left = nprime;                            // hang insurance
    while (p >= 0 && p < nprime && left-- > 0) {
        acc += x[(size_t)p * NCH + c];
        p = next[p];
    }
    acc += __shfl_xor(acc, 32);
    if (lane < 32)
        out[(size_t)c * NVOX + wv] = acc;
}

// ---------------- tier 3: atomic scatter (proven R5) -----------------------

__global__ void __launch_bounds__(256)
lss_scatter(const float* __restrict__ geom,
            const float* __restrict__ x,
            float* __restrict__ acc, int nprime, int c0, int cg) {
    int p = blockIdx.x * blockDim.x + threadIdx.x;
    if (p >= nprime) return;
    int v = voxel_of(geom, p);
    if (v < 0) return;

    float* dst = acc + (size_t)v * cg;
    const float* row = x + (size_t)p * NCH + c0;

    int k4 = cg >> 2;
    const float4* rv = (const float4*)row;
    for (int k = 0; k < k4; ++k) {
        float4 vv = rv[k];
        atomic_add_agent(dst + 4 * k + 0, vv.x);
        atomic_add_agent(dst + 4 * k + 1, vv.y);
        atomic_add_agent(dst + 4 * k + 2, vv.z);
        atomic_add_agent(dst + 4 * k + 3, vv.w);
    }
    for (int k = k4 << 2; k < cg; ++k)
        atomic_add_agent(dst + k, row[k]);
}

__global__ void __launch_bounds__(256)
lss_finalize(const float* __restrict__ acc, float* __restrict__ out,
             int c0, int cg) {
    int t = blockIdx.x * blockDim.x + threadIdx.x;
    if (t >= NVOX * cg) return;
    int cl = t / NVOX;
    int s  = t - cl * NVOX;
    out[(size_t)(c0 + cl) * NVOX + s] = acc[(size_t)s * cg + cl];
}

// ---------------------------------------------------------------------------

extern "C" void kernel_launch(void* const* d_in, const int* in_sizes, int n_in,
                              void* d_out, int out_size, void* d_ws, size_t ws_size,
                              hipStream_t stream) {
    const float* geom = (const float*)d_in[0];
    const float* x    = (const float*)d_in[1];
    int gsz = in_sizes[0], xsz = in_sizes[1];
    if (gsz > xsz) {  // defensive: geom (nprime*3) is the smaller input
        const float* tmp = geom; geom = x; x = tmp;
        int t2 = gsz; gsz = xsz; xsz = t2;
    }
    float* out = (float*)d_out;
    int nprime = xsz / NCH;  // 2,770,944
    int threads = 256;

    // tier 1: CSR buckets. cnt | extra | bucket, all int/f32 (4B).
    size_t need_csr = ((size_t)NVOX + (size_t)NVOX * NCH
                       + (size_t)NVOX * MAXPTS) * 4;  // ~46.2 MB
    if (ws_size >= need_csr) {
        int*   cnt    = (int*)d_ws;
        float* extra  = (float*)(cnt + NVOX);
        int*   bucket = (int*)(extra + (size_t)NVOX * NCH);
        // cnt + extra are contiguous -> single zeroing memset (5.28 MB)
        hipMemsetAsync(cnt, 0, ((size_t)NVOX + (size_t)NVOX * NCH) * 4, stream);
        int blocks_cnt = (nprime + threads - 1) / threads;
        lss_count<<<blocks_cnt, threads, 0, stream>>>(geom, x, cnt, extra,
                                                      bucket, nprime);
        int blocks_g = (NVOX + (threads / 64) - 1) / (threads / 64);  // 10000
        lss_gather_csr<<<blocks_g, threads, 0, stream>>>(x, cnt, extra, bucket,
                                                         out, nprime);
        return;
    }

    // tier 2: linked lists
    size_t need_ll = (size_t)(2 * NVOX + nprime) * sizeof(int);  // ~11.4 MB
    if (ws_size >= need_ll) {
        int* head2 = (int*)d_ws;
        int* next  = head2 + 2 * NVOX;
        hipMemsetAsync(head2, 0xFF, (size_t)2 * NVOX * sizeof(int), stream);
        int blocks_build = (nprime + threads - 1) / threads;
        lss_build<<<blocks_build, threads, 0, stream>>>(geom, head2, next, nprime);
        int blocks_gather = (NVOX + (threads / 64) - 1) / (threads / 64);
        lss_gather<<<blocks_gather, threads, 0, stream>>>(x, head2, next, out, nprime);
        return;
    }

    // tier 3: channel-grouped atomic scatter
    float* acc = (float*)d_ws;
    int cg = NCH;
    while (cg > 1 && (size_t)NVOX * cg * sizeof(float) > ws_size) cg >>= 1;
    int blocks_scatter = (nprime + threads - 1) / threads;
    for (int c0 = 0; c0 < NCH; c0 += cg) {
        hipMemsetAsync(acc, 0, (size_t)NVOX * cg * sizeof(float), stream);
        lss_scatter<<<blocks_scatter, threads, 0, stream>>>(geom, x, acc, nprime, c0, cg);
        int total = NVOX * cg;
        lss_finalize<<<(total + threads - 1) / threads, threads, 0, stream>>>(acc, out, c0, cg);
    }
}

// Round 4
// 618.500 us; speedup vs baseline: 1.1713x; 1.1713x over previous
//
#include <hip/hip_runtime.h>

// LiftSplatShoot voxel pooling, B=1, N=6, D=41, H=64, W=176, C=32, grid 200x200x1.
// nprime = 2,770,944 points. rank = ix*200 + iy (nx2=1, B=1).
// out[c*40000 + ix*200 + iy] = sum over points in voxel (ix,iy) of x[p][c].
//
// R6 (3921->611us): linked-list build (1 atomicExch/kept point) + wave-per-
//   voxel gather replaced 88.7M contended f32 atomics.
// R8 (611->724us, REGRESSED): CSR buckets. rocprof: lss_count ~289us (the
//   scattered 4B bucket stores cost ~64B line-RMW each vs LL's coalesced
//   next[] writes; plus ~80us device-atomic floor at ~25G/s), gather_csr
//   217us @ only 740GB/s / 6% VALU (index->row load chain, VGPR=12 -> ~2
//   loads in flight). Poison fill 216us is a fixed harness floor.
// R9: LL build with EIGHT chains per voxel (p&7) + gather walking 4 chains
//   per half-wave in parallel registers -> 8 independent row loads in
//   flight per wave, chase depth 26 -> 6.5, zero scattered stores.

#define NVOX   40000
#define NCH    32
#define NCHAIN 8

__device__ __forceinline__ void atomic_add_agent(float* p, float v) {
    __hip_atomic_fetch_add(p, v, __ATOMIC_RELAXED, __HIP_MEMORY_SCOPE_AGENT);
}

__device__ __forceinline__ int voxel_of(const float* __restrict__ geom, int p) {
    // Exact reference arithmetic: t = (g - (bx - dx/2)) / dx, trunc toward zero.
    float gx = geom[3 * (size_t)p + 0];
    float gy = geom[3 * (size_t)p + 1];
    float gz = geom[3 * (size_t)p + 2];
    float tx = (gx + 50.0f) / 0.5f;   // lo_x = -50 exact; /0.5 exact
    float ty = (gy + 50.0f) / 0.5f;
    float tz = (gz + 10.0f) / 20.0f;  // correctly-rounded IEEE f32 division
    int ix = (int)tx;  // trunc toward zero == astype(int32); (-1,0) -> 0 kept
    int iy = (int)ty;
    int iz = (int)tz;
    if (!((ix >= 0) && (ix < 200) && (iy >= 0) && (iy < 200) && (iz == 0)))
        return -1;
    return ix * 200 + iy;
}

// ---------------- tier 1: 8-chain linked lists + parallel-chase gather -----

// head: [NCHAIN][NVOX] chain heads (memset 0xFF -> -1). next: [nprime].
__global__ void __launch_bounds__(256)
lss_build8(const float* __restrict__ geom, int* __restrict__ head,
           int* __restrict__ next, int nprime) {
    int p = blockIdx.x * blockDim.x + threadIdx.x;
    if (p >= nprime) return;
    int v = voxel_of(geom, p);
    if (v < 0) return;
    int old = __hip_atomic_exchange(&head[(size_t)(p & (NCHAIN - 1)) * NVOX + v],
                                    p, __ATOMIC_RELAXED, __HIP_MEMORY_SCOPE_AGENT);
    next[p] = old;   // coalesced; consumed only by the next launch -> no race
}

// One wave per voxel. half h (32 lanes = 32 channels) walks chains 4h..4h+3
// simultaneously via 4 live pointer registers -> 8 independent 128B x-row
// loads + 8 next loads in flight per wave. All chain state is half-uniform
// (broadcast loads); only the x row load differs per lane (coalesced 128B).
__global__ void __launch_bounds__(256)
lss_gather8(const float* __restrict__ x, const int* __restrict__ head,
            const int* __restrict__ next, float* __restrict__ out, int nprime) {
    int wv = blockIdx.x * (blockDim.x >> 6) + (threadIdx.x >> 6);  // voxel
    if (wv >= NVOX) return;
    int lane = threadIdx.x & 63;
    int half = lane >> 5;
    int c    = lane & 31;

    const int* h = head + (size_t)(4 * half) * NVOX + wv;
    int p0 = h[0 * NVOX];
    int p1 = h[1 * NVOX];
    int p2 = h[2 * NVOX];
    int p3 = h[3 * NVOX];

    float acc = 0.0f;
    int left = nprime;  // hang insurance: chains are acyclic by construction
    // dead = -1 (all bits); any valid p has bit31=0, so AND==-1 iff all dead.
    while (((p0 & p1 & p2 & p3) != -1) && left > 0) {
        if ((unsigned)p0 < (unsigned)nprime) { acc += x[(size_t)p0 * NCH + c]; p0 = next[p0]; } else p0 = -1;
        if ((unsigned)p1 < (unsigned)nprime) { acc += x[(size_t)p1 * NCH + c]; p1 = next[p1]; } else p1 = -1;
        if ((unsigned)p2 < (unsigned)nprime) { acc += x[(size_t)p2 * NCH + c]; p2 = next[p2]; } else p2 = -1;
        if ((unsigned)p3 < (unsigned)nprime) { acc += x[(size_t)p3 * NCH + c]; p3 = next[p3]; } else p3 = -1;
        left -= 4;
    }
    acc += __shfl_xor(acc, 32);             // combine the two halves
    if (lane < 32)
        out[(size_t)c * NVOX + wv] = acc;   // (C, 200, 200), every voxel written
}

// ---------------- tier 2: 2-chain linked lists (proven R7, 611us) ----------

__global__ void __launch_bounds__(256)
lss_build(const float* __restrict__ geom, int* __restrict__ head2,
          int* __restrict__ next, int nprime) {
    int p = blockIdx.x * blockDim.x + threadIdx.x;
    if (p >= nprime) return;
    int v = voxel_of(geom, p);
    if (v < 0) return;
    int slot = (p & 1) * NVOX + v;
    int old = __hip_atomic_exchange(&head2[slot], p,
                                    __ATOMIC_RELAXED, __HIP_MEMORY_SCOPE_AGENT);
    next[p] = old;
}

__global__ void __launch_bounds__(256)
lss_gather(const float* __restrict__ x, const int* __restrict__ head2,
           const int* __restrict__ next, float* __restrict__ out, int nprime) {
    int wv = blockIdx.x * (blockDim.x >> 6) + (threadIdx.x >> 6);
    if (wv >= NVOX) return;
    int lane = threadIdx.x & 63;
    int half = lane >> 5;
    int c    = lane & 31;

    float acc = 0.0f;
    int p = head2[half * NVOX + wv];
    int left = nprime;
    while (p >= 0 && p < nprime && left-- > 0) {
        acc += x[(size_t)p * NCH + c];
        p = next[p];
    }
    acc += __shfl_xor(acc, 32);
    if (lane < 32)
        out[(size_t)c * NVOX + wv] = acc;
}

// ---------------- tier 3: atomic scatter (proven R5) -----------------------

__global__ void __launch_bounds__(256)
lss_scatter(const float* __restrict__ geom,
            const float* __restrict__ x,
            float* __restrict__ acc, int nprime, int c0, int cg) {
    int p = blockIdx.x * blockDim.x + threadIdx.x;
    if (p >= nprime) return;
    int v = voxel_of(geom, p);
    if (v < 0) return;

    float* dst = acc + (size_t)v * cg;
    const float* row = x + (size_t)p * NCH + c0;

    int k4 = cg >> 2;
    const float4* rv = (const float4*)row;
    for (int k = 0; k < k4; ++k) {
        float4 vv = rv[k];
        atomic_add_agent(dst + 4 * k + 0, vv.x);
        atomic_add_agent(dst + 4 * k + 1, vv.y);
        atomic_add_agent(dst + 4 * k + 2, vv.z);
        atomic_add_agent(dst + 4 * k + 3, vv.w);
    }
    for (int k = k4 << 2; k < cg; ++k)
        atomic_add_agent(dst + k, row[k]);
}

__global__ void __launch_bounds__(256)
lss_finalize(const float* __restrict__ acc, float* __restrict__ out,
             int c0, int cg) {
    int t = blockIdx.x * blockDim.x + threadIdx.x;
    if (t >= NVOX * cg) return;
    int cl = t / NVOX;
    int s  = t - cl * NVOX;
    out[(size_t)(c0 + cl) * NVOX + s] = acc[(size_t)s * cg + cl];
}

// ---------------------------------------------------------------------------

extern "C" void kernel_launch(void* const* d_in, const int* in_sizes, int n_in,
                              void* d_out, int out_size, void* d_ws, size_t ws_size,
                              hipStream_t stream) {
    const float* geom = (const float*)d_in[0];
    const float* x    = (const float*)d_in[1];
    int gsz = in_sizes[0], xsz = in_sizes[1];
    if (gsz > xsz) {  // defensive: geom (nprime*3) is the smaller input
        const float* tmp = geom; geom = x; x = tmp;
        int t2 = gsz; gsz = xsz; xsz = t2;
    }
    float* out = (float*)d_out;
    int nprime = xsz / NCH;  // 2,770,944
    int threads = 256;

    // tier 1: 8-chain linked lists. head | next.
    size_t need8 = ((size_t)NCHAIN * NVOX + (size_t)nprime) * sizeof(int);  // ~12.4 MB
    if (ws_size >= need8) {
        int* head = (int*)d_ws;
        int* next = head + (size_t)NCHAIN * NVOX;
        hipMemsetAsync(head, 0xFF, (size_t)NCHAIN * NVOX * sizeof(int), stream);
        int blocks_build = (nprime + threads - 1) / threads;
        lss_build8<<<blocks_build, threads, 0, stream>>>(geom, head, next, nprime);
        int blocks_g = (NVOX + (threads / 64) - 1) / (threads / 64);  // 10000
        lss_gather8<<<blocks_g, threads, 0, stream>>>(x, head, next, out, nprime);
        return;
    }

    // tier 2: 2-chain linked lists
    size_t need_ll = (size_t)(2 * NVOX + nprime) * sizeof(int);  // ~11.4 MB
    if (ws_size >= need_ll) {
        int* head2 = (int*)d_ws;
        int* next  = head2 + 2 * NVOX;
        hipMemsetAsync(head2, 0xFF, (size_t)2 * NVOX * sizeof(int), stream);
        int blocks_build = (nprime + threads - 1) / threads;
        lss_build<<<blocks_build, threads, 0, stream>>>(geom, head2, next, nprime);
        int blocks_gather = (NVOX + (threads / 64) - 1) / (threads / 64);
        lss_gather<<<blocks_gather, threads, 0, stream>>>(x, head2, next, out, nprime);
        return;
    }

    // tier 3: channel-grouped atomic scatter
    float* acc = (float*)d_ws;
    int cg = NCH;
    while (cg > 1 && (size_t)NVOX * cg * sizeof(float) > ws_size) cg >>= 1;
    int blocks_scatter = (nprime + threads - 1) / threads;
    for (int c0 = 0; c0 < NCH; c0 += cg) {
        hipMemsetAsync(acc, 0, (size_t)NVOX * cg * sizeof(float), stream);
        lss_scatter<<<blocks_scatter, threads, 0, stream>>>(geom, x, acc, nprime, c0, cg);
        int total = NVOX * cg;
        lss_finalize<<<(total + threads - 1) / threads, threads, 0, stream>>>(acc, out, c0, cg);
    }
}